// Round 4
// baseline (1207.444 us; speedup 1.0000x reference)
//
#include <hip/hip_runtime.h>
#include <math.h>

#define BB 8
#define CC 128
#define NN 2048
#define KK 10
#define TWO_CC 256
#define DEP 16
#define MYS 4            // candidate-range splits per row (quarters of 512)

// async global->LDS, 16B per lane; lds dest = wave-uniform base + lane*16
__device__ __forceinline__ void gload16(const float* g, float* l) {
    __builtin_amdgcn_global_load_lds((const __attribute__((address_space(1))) void*)g,
                                     (__attribute__((address_space(3))) void*)l, 16, 0, 0);
}

// ---------------- squared column norms in f64 ----------------
__global__ __launch_bounds__(256) void k_xx(const float* __restrict__ h, double* __restrict__ xx) {
    int t = blockIdx.x * 256 + threadIdx.x;
    if (t >= BB * NN) return;
    int b = t / NN, n = t % NN;
    const float* p = h + (size_t)b * CC * NN + n;
    double s = 0.0;
#pragma unroll
    for (int c = 0; c < CC; ++c) {
        double v = (double)p[(size_t)c * NN];
        s += v * v;
    }
    xx[t] = s;
}

// ---------------- f32 screen with packed u32 keys + register bitonic merge ----------------
// block: 64 rows of batch b, quarter my of candidates. 256 thr; tx=t&7 (8 cols), ty=t>>3 (2 rows).
// key = sortable(f32 pd) & ~511 | (511 - rel);  rel = m - my*512.  Top-16 per (row, quarter).
__global__ __launch_bounds__(256, 4) void k_knn(const float* __restrict__ h, const double* __restrict__ xxg,
                                                unsigned* __restrict__ cand) {
    __shared__ __align__(16) float At[128 * 64];     // 32KB  At[c][j]
    __shared__ __align__(16) float Bq[2][16 * 64];   // 2x4KB double-buffered 16-ch chunks

    int t = threadIdx.x;
    int tx = t & 7, ty = t >> 3;                     // rows 2ty, 2ty+1
    int w = t >> 6, lane = t & 63;
    int b = blockIdx.z, my = blockIdx.y, n0 = blockIdx.x * 64;
    const float* hb = h + (size_t)b * CC * NN;

    // stage A-tile once (32KB): slot s -> channel s>>4, cols (s&15)*4
#pragma unroll
    for (int i = 0; i < 8; ++i) {
        int sb = (i * 4 + w) * 64;
        int g = sb + lane;
        gload16(hb + (size_t)(g >> 4) * NN + n0 + ((g & 15) << 2), At + 4 * sb);
    }

    auto stageChunk = [&](int s, int buf) {
        int c0 = (s & 7) * 16;
        int m0 = my * 512 + (s >> 3) * 64;
        int sb = w * 64;
        int g = sb + lane;
        gload16(hb + (size_t)(c0 + (g >> 4)) * NN + m0 + ((g & 15) << 2), Bq[buf] + 4 * sb);
    };
    auto ins = [](unsigned (&L)[DEP], unsigned k) {
        if (k > L[DEP - 1]) {
            L[DEP - 1] = k;
#pragma unroll
            for (int q = DEP - 1; q >= 1; --q) {
                unsigned a = L[q - 1], c = L[q];
                L[q - 1] = a > c ? a : c;
                L[q]     = a > c ? c : a;
            }
        }
    };

    unsigned L[2][DEP];
#pragma unroll
    for (int rr = 0; rr < 2; ++rr)
#pragma unroll
        for (int q = 0; q < DEP; ++q) L[rr][q] = 0u;

    float acc[2][8] = {};
    double xsd[8];

    stageChunk(0, 0);
    __syncthreads();                                 // drains A + chunk0

    for (int s = 0; s < 64; ++s) {                   // s = mt*8 + ch  (8 mt x 8 chunks of 16 ch)
        int buf = s & 1;
        if (s + 1 < 64) stageChunk(s + 1, buf ^ 1);
        if ((s & 7) == 0) {
            int m0 = my * 512 + (s >> 3) * 64;
#pragma unroll
            for (int j = 0; j < 8; ++j) xsd[j] = xxg[b * NN + m0 + 8 * tx + j];
        }
        {
            int cb = (s & 7) * 16;
            const float* pA = At + cb * 64 + 2 * ty;
            const float* pB = Bq[buf] + 8 * tx;
#pragma unroll
            for (int kk = 0; kk < 16; ++kk) {
                float2 af  = *(const float2*)(pA + kk * 64);
                float4 bf0 = *(const float4*)(pB + kk * 64);
                float4 bf1 = *(const float4*)(pB + kk * 64 + 4);
                acc[0][0] += af.x * bf0.x; acc[0][1] += af.x * bf0.y;
                acc[0][2] += af.x * bf0.z; acc[0][3] += af.x * bf0.w;
                acc[0][4] += af.x * bf1.x; acc[0][5] += af.x * bf1.y;
                acc[0][6] += af.x * bf1.z; acc[0][7] += af.x * bf1.w;
                acc[1][0] += af.y * bf0.x; acc[1][1] += af.y * bf0.y;
                acc[1][2] += af.y * bf0.z; acc[1][3] += af.y * bf0.w;
                acc[1][4] += af.y * bf1.x; acc[1][5] += af.y * bf1.y;
                acc[1][6] += af.y * bf1.z; acc[1][7] += af.y * bf1.w;
            }
        }
        if ((s & 7) == 7) {
            float xsf[8];
#pragma unroll
            for (int j = 0; j < 8; ++j) xsf[j] = (float)xsd[j];
            int binv = 511 - (s >> 3) * 64 - 8 * tx;
#pragma unroll
            for (int rr = 0; rr < 2; ++rr)
#pragma unroll
                for (int j = 0; j < 8; ++j) {
                    float v = fmaf(2.f, acc[rr][j], -xsf[j]);
                    unsigned u = __float_as_uint(v);
                    u ^= (unsigned)((int)u >> 31) | 0x80000000u;
                    unsigned key = (u & 0xFFFFFE00u) | (unsigned)(binv - j);
                    ins(L[rr], key);
                }
#pragma unroll
            for (int rr = 0; rr < 2; ++rr)
#pragma unroll
                for (int j = 0; j < 8; ++j) acc[rr][j] = 0.f;
        }
        __syncthreads();
    }

    // register bitonic merge across tx (masks 1,2,4): all 8 lanes converge to the row's top-16
#pragma unroll
    for (int rr = 0; rr < 2; ++rr) {
#pragma unroll
        for (int rnd = 0; rnd < 3; ++rnd) {
            int msk = 1 << rnd;
            unsigned P[DEP], C[DEP];
#pragma unroll
            for (int q = 0; q < DEP; ++q) P[q] = (unsigned)__shfl_xor((int)L[rr][q], msk, 64);
#pragma unroll
            for (int q = 0; q < DEP; ++q) {
                unsigned pv = P[DEP - 1 - q];
                C[q] = L[rr][q] > pv ? L[rr][q] : pv;       // top-16 of union (bitonic)
            }
#pragma unroll
            for (int d = 8; d >= 1; d >>= 1)
#pragma unroll
                for (int i = 0; i < DEP; ++i)
                    if (!(i & d)) {
                        unsigned a = C[i], c2 = C[i + d];
                        C[i]     = a > c2 ? a : c2;
                        C[i + d] = a > c2 ? c2 : a;
                    }
#pragma unroll
            for (int q = 0; q < DEP; ++q) L[rr][q] = C[q];
        }
    }
    if (tx == 0) {
#pragma unroll
        for (int rr = 0; rr < 2; ++rr) {
            int n = n0 + 2 * ty + rr;
            unsigned* op = cand + ((size_t)(b * MYS + my) * NN + n) * DEP;
#pragma unroll
            for (int q = 0; q < DEP; ++q) op[q] = L[rr][q];
        }
    }
}

// ---------------- fused exact f64 re-score of 64 candidates + top-10 + neighbor mean ----
// 4 waves/block, 1 row/wave. Lane owns candidate lane (4 quarters x 16). Dot computed as
// 8 passes of (8 cands x 8 ch-slices): 3 xor-shfls in 8-lane group + 1 transpose shfl.
__global__ __launch_bounds__(256) void k_rg(const float* __restrict__ ht, const double* __restrict__ xxg,
                                            const unsigned* __restrict__ cand, float* __restrict__ M) {
    int wv = threadIdx.x >> 6, lane = threadIdx.x & 63;
    int r = blockIdx.x * 4 + wv;
    int b = r >> 11, n = r & (NN - 1);
    const float* base = ht + (size_t)b * NN * CC;

    int qr = lane >> 4, q16 = lane & 15;
    unsigned key = cand[((size_t)(b * MYS + qr) * NN + n) * DEP + q16];
    int m = qr * 512 + 511 - (int)(key & 511u);
    double xxm = xxg[b * NN + m];

    int cseg = (lane & 7) * 4;                       // this lane's 4-ch unit within each 32-ch block
    double xd[16];
#pragma unroll
    for (int j = 0; j < 4; ++j) {
        float4 xv = *(const float4*)(base + (size_t)n * CC + 32 * j + cseg);
        xd[4 * j + 0] = (double)xv.x; xd[4 * j + 1] = (double)xv.y;
        xd[4 * j + 2] = (double)xv.z; xd[4 * j + 3] = (double)xv.w;
    }

    double dtot = 0.0;
#pragma unroll
    for (int p = 0; p < 8; ++p) {
        int mp = __shfl(m, p * 8 + (lane >> 3), 64);
        const float* pm = base + (size_t)mp * CC + cseg;
        double a = 0.0;
#pragma unroll
        for (int j = 0; j < 4; ++j) {
            float4 f = *(const float4*)(pm + 32 * j);
            a += xd[4 * j + 0] * (double)f.x + xd[4 * j + 1] * (double)f.y
               + xd[4 * j + 2] * (double)f.z + xd[4 * j + 3] * (double)f.w;
        }
        a += __shfl_xor(a, 1, 64);
        a += __shfl_xor(a, 2, 64);
        a += __shfl_xor(a, 4, 64);                   // 8-lane group sum -> full 128-ch dot
        double got = __shfl(a, (lane & 7) * 8 + (lane >> 3), 64);   // transpose collect
        if ((lane >> 3) == p) dtot = got;            // lane l holds dot of candidate l
    }

    double sv = 2.0 * dtot - xxm;
    int si = m;
    float sx = 0.f, sy = 0.f;
#pragma unroll
    for (int rr = 0; rr < 10; ++rr) {
        double bv = sv; int bi = si;
#pragma unroll
        for (int off = 32; off; off >>= 1) {
            double ov = __shfl_xor(bv, off, 64);
            int oi = __shfl_xor(bi, off, 64);
            bool tk = (ov > bv) || (ov == bv && oi < bi);
            bv = tk ? ov : bv; bi = tk ? oi : bi;
        }
        float2 pm2 = *(const float2*)(base + (size_t)bi * CC + 2 * lane);
        sx += pm2.x; sy += pm2.y;                    // rank-order summation (as before)
        if (si == bi) sv = -1.0e301;                 // knock out winner
    }
    float2 o; o.x = sx * (1.f / KK); o.y = sy * (1.f / KK);
    *(float2*)(M + (size_t)r * CC + 2 * lane) = o;
}

// ---------------- transpose: ht[b][n][c] = h[b][c][n] ----------------
__global__ __launch_bounds__(256) void k_tr(const float* __restrict__ h, float* __restrict__ ht) {
    __shared__ float tile[32][33];
    int b = blockIdx.z, c0 = blockIdx.y * 32, n0 = blockIdx.x * 32;
    int tx = threadIdx.x & 31, tyy = threadIdx.x >> 5;
    const float* hb = h + (size_t)b * CC * NN;
#pragma unroll
    for (int i = 0; i < 4; ++i)
        tile[tyy + i * 8][tx] = hb[(size_t)(c0 + tyy + i * 8) * NN + n0 + tx];
    __syncthreads();
    float* htb = ht + (size_t)b * NN * CC;
#pragma unroll
    for (int i = 0; i < 4; ++i)
        htb[(size_t)(n0 + tyy + i * 8) * CC + c0 + tx] = tile[tx][tyy + i * 8];
}

// ---------------- y = Wa*M + (Wb-Wa)*h + bias ----------------
__global__ __launch_bounds__(256) void k_gemm(const float* __restrict__ M, const float* __restrict__ h,
                                              const float* __restrict__ W, const float* __restrict__ bias,
                                              float* __restrict__ y) {
    __shared__ float Ws[64][33];
    __shared__ float Xs[32][65];
    int b = blockIdx.z;
    int o0 = blockIdx.y * 64;
    int n0 = blockIdx.x * 64;
    int tid = threadIdx.x;
    int tx = tid & 15, ty = tid >> 4;
    float acc[4][4] = {};
    const float* Mb = M + (size_t)b * NN * CC;
    const float* hb = h + (size_t)b * CC * NN;

    for (int c0 = 0; c0 < CC; c0 += 32) {
        for (int i = tid; i < 64 * 32; i += 256) {
            int c = i & 31, o = i >> 5;
            Ws[o][c] = W[(size_t)(o0 + o) * TWO_CC + c0 + c];
        }
        for (int i = tid; i < 64 * 32; i += 256) {
            int c = i & 31, nn = i >> 5;
            Xs[c][nn] = Mb[(size_t)(n0 + nn) * CC + c0 + c];
        }
        __syncthreads();
        for (int c = 0; c < 32; ++c) {
            float a[4], bb[4];
#pragma unroll
            for (int q = 0; q < 4; ++q) { a[q] = Ws[ty * 4 + q][c]; bb[q] = Xs[c][tx * 4 + q]; }
#pragma unroll
            for (int i2 = 0; i2 < 4; ++i2)
#pragma unroll
                for (int j = 0; j < 4; ++j) acc[i2][j] += a[i2] * bb[j];
        }
        __syncthreads();
    }
    for (int c0 = 0; c0 < CC; c0 += 32) {
        for (int i = tid; i < 64 * 32; i += 256) {
            int c = i & 31, o = i >> 5;
            const float* wr = W + (size_t)(o0 + o) * TWO_CC;
            Ws[o][c] = wr[CC + c0 + c] - wr[c0 + c];
        }
        for (int i = tid; i < 64 * 32; i += 256) {
            int nn = i & 63, c = i >> 6;
            Xs[c][nn] = hb[(size_t)(c0 + c) * NN + n0 + nn];
        }
        __syncthreads();
        for (int c = 0; c < 32; ++c) {
            float a[4], bb[4];
#pragma unroll
            for (int q = 0; q < 4; ++q) { a[q] = Ws[ty * 4 + q][c]; bb[q] = Xs[c][tx * 4 + q]; }
#pragma unroll
            for (int i2 = 0; i2 < 4; ++i2)
#pragma unroll
                for (int j = 0; j < 4; ++j) acc[i2][j] += a[i2] * bb[j];
        }
        __syncthreads();
    }
#pragma unroll
    for (int i2 = 0; i2 < 4; ++i2) {
        int o = o0 + ty * 4 + i2;
        float bv = bias[o];
#pragma unroll
        for (int j = 0; j < 4; ++j)
            y[((size_t)b * CC + o) * NN + n0 + tx * 4 + j] = acc[i2][j] + bv;
    }
}

// ---------------- per-(b,o) mean/var(ddof=1), relu, optional residual ----------------
__global__ __launch_bounds__(256) void k_norm(const float* __restrict__ y, const float* __restrict__ res,
                                              float* __restrict__ out, int add_res) {
    int bo = blockIdx.x;
    const float* row = y + (size_t)bo * NN;
    float s = 0.f, s2 = 0.f;
    for (int n = threadIdx.x; n < NN; n += 256) {
        float v = row[n];
        s += v;
        s2 += v * v;
    }
#pragma unroll
    for (int off = 32; off > 0; off >>= 1) {
        s += __shfl_down(s, off, 64);
        s2 += __shfl_down(s2, off, 64);
    }
    __shared__ float ss[4], ss2[4];
    int wave = threadIdx.x >> 6, lane = threadIdx.x & 63;
    if (lane == 0) { ss[wave] = s; ss2[wave] = s2; }
    __syncthreads();
    if (threadIdx.x == 0) {
        float S = ss[0] + ss[1] + ss[2] + ss[3];
        float S2 = ss2[0] + ss2[1] + ss2[2] + ss2[3];
        float mean = S * (1.f / NN);
        float var = (S2 - S * mean) * (1.f / (NN - 1));
        ss[0] = mean;
        ss2[0] = rsqrtf(var + 1e-3f);
    }
    __syncthreads();
    float mean = ss[0], inv = ss2[0];
    for (int n = threadIdx.x; n < NN; n += 256) {
        float v = (row[n] - mean) * inv;
        v = fmaxf(v, 0.f);
        if (add_res) v += res[(size_t)bo * NN + n];
        out[(size_t)bo * NN + n] = v;
    }
}

extern "C" void kernel_launch(void* const* d_in, const int* in_sizes, int n_in,
                              void* d_out, int out_size, void* d_ws, size_t ws_size,
                              hipStream_t stream) {
    const float* x  = (const float*)d_in[0];
    const float* W1 = (const float*)d_in[1];
    const float* b1 = (const float*)d_in[2];
    const float* W2 = (const float*)d_in[3];
    const float* b2 = (const float*)d_in[4];
    float* out = (float*)d_out;

    char* wsb = (char*)d_ws;
    double* xx = (double*)wsb;                          // 8*2048 f64 = 131072 B
    char* p = wsb + (size_t)BB * NN * 8;
    float* ht = (float*)p;    p += (size_t)BB * NN * CC * 4;    // 8 MB
    float* M  = (float*)p;    p += (size_t)BB * NN * CC * 4;    // 8 MB
    float* y  = (float*)p;    p += (size_t)BB * CC * NN * 4;    // 8 MB
    float* h1 = (float*)p;                                      // 8 MB

    // packed screened keys (16 per row per quarter) live in y's region —
    // y is dead until k_gemm, and cand is consumed by k_rg before that.
    unsigned* cand = (unsigned*)y;                              // 8*4*2048*16*4 = 4 MB

    auto layer = [&](const float* hin, const float* Wt, const float* bt, float* hout, int add_res) {
        hipLaunchKernelGGL(k_xx, dim3((BB * NN) / 256), dim3(256), 0, stream, hin, xx);
        hipLaunchKernelGGL(k_tr, dim3(NN / 32, CC / 32, BB), dim3(256), 0, stream, hin, ht);
        hipLaunchKernelGGL(k_knn, dim3(NN / 64, MYS, BB), dim3(256), 0, stream, hin, xx, cand);
        hipLaunchKernelGGL(k_rg, dim3(BB * NN / 4), dim3(256), 0, stream, ht, xx, cand, M);
        hipLaunchKernelGGL(k_gemm, dim3(NN / 64, CC / 64, BB), dim3(256), 0, stream, M, hin, Wt, bt, y);
        hipLaunchKernelGGL(k_norm, dim3(BB * CC), dim3(256), 0, stream, y, x, hout, add_res);
    };

    layer(x, W1, b1, h1, 0);
    layer(h1, W2, b2, out, 1);
}

// Round 5
// 414.425 us; speedup vs baseline: 2.9135x; 2.9135x over previous
//
#include <hip/hip_runtime.h>
#include <math.h>

#define BB 8
#define CC 128
#define NN 2048
#define KK 10
#define TWO_CC 256
#define DEP 16
#define MYS 2            // candidate-range halves per row (1024 each)

typedef __attribute__((ext_vector_type(8))) short bf16x8;
typedef __attribute__((ext_vector_type(4))) float f32x4;

// async global->LDS, 16B per lane; lds dest = wave-uniform base + lane*16
__device__ __forceinline__ void gload16(const void* g, void* l) {
    __builtin_amdgcn_global_load_lds((const __attribute__((address_space(1))) void*)g,
                                     (__attribute__((address_space(3))) void*)l, 16, 0, 0);
}

// descending top-16 insert of a packed u32 key
__device__ __forceinline__ void ins16(unsigned (&L)[DEP], unsigned k) {
    if (k > L[DEP - 1]) {
        L[DEP - 1] = k;
#pragma unroll
        for (int q = DEP - 1; q >= 1; --q) {
            unsigned a = L[q - 1], c = L[q];
            L[q - 1] = a > c ? a : c;
            L[q]     = a > c ? c : a;
        }
    }
}

// ---------------- squared column norms (f64 exact + f32 copy for the screen) ----------------
__global__ __launch_bounds__(256) void k_xx(const float* __restrict__ h, double* __restrict__ xx,
                                            float* __restrict__ xxf) {
    int t = blockIdx.x * 256 + threadIdx.x;
    if (t >= BB * NN) return;
    int b = t / NN, n = t % NN;
    const float* p = h + (size_t)b * CC * NN + n;
    double s = 0.0;
#pragma unroll
    for (int c = 0; c < CC; ++c) {
        double v = (double)p[(size_t)c * NN];
        s += v * v;
    }
    xx[t] = s;
    xxf[t] = (float)s;
}

// ---------------- fused transpose + bf16 hi/lo split ----------------
// ht[b][n][c] = h[b][c][n] (f32); hti/htlo = bf16 hi/lo split of the same, RTN.
__global__ __launch_bounds__(256) void k_bf(const float* __restrict__ h, float* __restrict__ ht,
                                            unsigned short* __restrict__ hti, unsigned short* __restrict__ htlo) {
    __shared__ float tile[32][33];
    int b = blockIdx.z, c0 = blockIdx.y * 32, n0 = blockIdx.x * 32;
    int tx = threadIdx.x & 31, tyy = threadIdx.x >> 5;
    const float* hb = h + (size_t)b * CC * NN;
#pragma unroll
    for (int i = 0; i < 4; ++i)
        tile[tyy + i * 8][tx] = hb[(size_t)(c0 + tyy + i * 8) * NN + n0 + tx];
    __syncthreads();
    size_t ob = (size_t)b * NN * CC;
#pragma unroll
    for (int i = 0; i < 4; ++i) {
        int n = n0 + tyy + i * 8, c = c0 + tx;
        float v = tile[tx][tyy + i * 8];
        unsigned uu = __float_as_uint(v);
        unsigned hbits = (uu + 0x7FFFu + ((uu >> 16) & 1u)) >> 16;        // RTN bf16
        float hf = __uint_as_float(hbits << 16);
        float lof = v - hf;
        unsigned ul = __float_as_uint(lof);
        unsigned lbits = (ul + 0x7FFFu + ((ul >> 16) & 1u)) >> 16;
        ht[ob + (size_t)n * CC + c] = v;
        hti[ob + (size_t)n * CC + c] = (unsigned short)hbits;
        htlo[ob + (size_t)n * CC + c] = (unsigned short)lbits;
    }
}

// ---------------- MFMA hi/lo screen + packed-key top-16 per (row, half) ----------------
// block: 64 rows (n0..+63) x half my of candidates (1024). 4 waves; wave owns 16 rows.
// LDS: A hi/lo [64][128] bf16 (32KB) + B double-buffered [32][128] hi/lo (2x16KB) = 64KB.
// XOR-swizzle ((row&7)<<4) applied on the GLOBAL source (staging) and on ds_read addrs.
__global__ __launch_bounds__(256, 2) void k_knn(const unsigned short* __restrict__ hti,
                                                const unsigned short* __restrict__ htlo,
                                                const float* __restrict__ xxf,
                                                unsigned* __restrict__ cand) {
    __shared__ __align__(16) char smem[65536];
    int t = threadIdx.x;
    int lane = t & 63, wv = t >> 6;
    int b = blockIdx.z, my = blockIdx.y, n0 = blockIdx.x * 64;

    const unsigned short* h0 = hti + (size_t)b * NN * CC;
    const unsigned short* h1 = htlo + (size_t)b * NN * CC;

    // ---- stage A-tile once (hi: [0,16K), lo: [16K,32K)) ----
#pragma unroll
    for (int j = 0; j < 8; ++j) {
        const unsigned short* hs = (j >> 2) ? h1 : h0;
        int q = j & 3;
        int sidx = q * 256 + wv * 64 + lane;
        int n = sidx >> 4, ch = sidx & 15;
        gload16(hs + (size_t)(n0 + n) * CC + ((ch ^ (n & 7)) << 3),
                smem + (j >> 2) * 16384 + (q * 256 + wv * 64) * 16);
    }

    auto stageB = [&](int mt, int buf) {
        int m0b = my * 1024 + mt * 32;
#pragma unroll
        for (int j = 0; j < 4; ++j) {
            const unsigned short* hs = (j >> 1) ? h1 : h0;
            int q = j & 1;
            int sidx = q * 256 + wv * 64 + lane;
            int mr = sidx >> 4, ch = sidx & 15;
            gload16(hs + (size_t)(m0b + mr) * CC + ((ch ^ (mr & 7)) << 3),
                    smem + 32768 + buf * 16384 + (j >> 1) * 8192 + (q * 256 + wv * 64) * 16);
        }
    };

    unsigned L[4][DEP];
#pragma unroll
    for (int r = 0; r < 4; ++r)
#pragma unroll
        for (int q = 0; q < DEP; ++q) L[r][q] = 0u;

    stageB(0, 0);
    __syncthreads();

    // hoist this wave's A fragments (16 rows x 128 k, hi+lo)
    bf16x8 ahi[4], alo[4];
    {
        int abase = (wv * 16 + (lane & 15)) * 256;
        int swz = (lane & 7) << 4;
#pragma unroll
        for (int ks = 0; ks < 4; ++ks) {
            int off = (abase + ks * 64 + ((lane >> 4) << 4)) ^ swz;
            ahi[ks] = *(const bf16x8*)(smem + off);
            alo[ks] = *(const bf16x8*)(smem + 16384 + off);
        }
    }

    const float* xb = xxf + b * NN;
    int buf = 0;
    for (int mt = 0; mt < 32; ++mt) {
        if (mt + 1 < 32) stageB(mt + 1, buf ^ 1);
        const char* Bb = smem + 32768 + buf * 16384;
        int m0 = my * 1024 + mt * 32;
#pragma unroll
        for (int cs = 0; cs < 2; ++cs) {
            float xm = xb[m0 + cs * 16 + (lane & 15)];
            f32x4 Cf = {0.f, 0.f, 0.f, 0.f};
            int rb = (cs * 16 + (lane & 15)) * 256;
            int swz = (lane & 7) << 4;
#pragma unroll
            for (int ks = 0; ks < 4; ++ks) {
                int off = (rb + ks * 64 + ((lane >> 4) << 4)) ^ swz;
                bf16x8 bh = *(const bf16x8*)(Bb + off);
                bf16x8 bl = *(const bf16x8*)(Bb + 8192 + off);
                Cf = __builtin_amdgcn_mfma_f32_16x16x32_bf16(ahi[ks], bh, Cf, 0, 0, 0);
                Cf = __builtin_amdgcn_mfma_f32_16x16x32_bf16(ahi[ks], bl, Cf, 0, 0, 0);
                Cf = __builtin_amdgcn_mfma_f32_16x16x32_bf16(alo[ks], bh, Cf, 0, 0, 0);
            }
            unsigned invrel = 1023u - (unsigned)(mt * 32 + cs * 16 + (lane & 15));
#pragma unroll
            for (int r = 0; r < 4; ++r) {
                float v = fmaf(2.f, Cf[r], -xm);
                unsigned u = __float_as_uint(v);
                u ^= (unsigned)((int)u >> 31) | 0x80000000u;
                ins16(L[r], (u & 0xFFFFFC00u) | invrel);
            }
        }
        __syncthreads();
        buf ^= 1;
    }

    // register bitonic merge across the 16 lanes of each row-group (masks 1,2,4,8)
#pragma unroll
    for (int r = 0; r < 4; ++r)
#pragma unroll
        for (int rnd = 0; rnd < 4; ++rnd) {
            unsigned C[DEP];
#pragma unroll
            for (int q = 0; q < DEP; ++q) {
                unsigned pv = (unsigned)__shfl_xor((int)L[r][DEP - 1 - q], 1 << rnd, 64);
                C[q] = L[r][q] > pv ? L[r][q] : pv;
            }
#pragma unroll
            for (int d = 8; d >= 1; d >>= 1)
#pragma unroll
                for (int i = 0; i < DEP; ++i)
                    if (!(i & d)) {
                        unsigned a = C[i], c2 = C[i + d];
                        C[i]     = a > c2 ? a : c2;
                        C[i + d] = a > c2 ? c2 : a;
                    }
#pragma unroll
            for (int q = 0; q < DEP; ++q) L[r][q] = C[q];
        }

    if ((lane & 15) == 0) {
        int g = lane >> 4;
#pragma unroll
        for (int r = 0; r < 4; ++r) {
            int n = n0 + wv * 16 + g * 4 + r;
            unsigned* op = cand + ((size_t)(b * MYS + my) * NN + n) * DEP;
#pragma unroll
            for (int q = 0; q < DEP; ++q) op[q] = L[r][q];
        }
    }
}

// ---------------- fused exact f64 re-score of 32 candidates + top-10 + neighbor mean ----
// 4 waves/block, 1 row/wave. Lanes 0..31 own candidates (2 halves x 16).
__global__ __launch_bounds__(256) void k_rg(const float* __restrict__ ht, const double* __restrict__ xxg,
                                            const unsigned* __restrict__ cand, float* __restrict__ M) {
    int wv = threadIdx.x >> 6, lane = threadIdx.x & 63;
    int r = blockIdx.x * 4 + wv;
    int b = r >> 11, n = r & (NN - 1);
    const float* base = ht + (size_t)b * NN * CC;

    bool act = lane < 32;
    int half = (lane >> 4) & 1, q16 = lane & 15;
    int m = n;
    if (act) {
        unsigned key = cand[((size_t)(b * MYS + half) * NN + n) * DEP + q16];
        m = half * 1024 + 1023 - (int)(key & 1023u);
    }
    double xxm = xxg[b * NN + m];

    int cseg = (lane & 7) * 4;                       // this lane's 4-ch unit within each 32-ch block
    double xd[16];
#pragma unroll
    for (int j = 0; j < 4; ++j) {
        float4 xv = *(const float4*)(base + (size_t)n * CC + 32 * j + cseg);
        xd[4 * j + 0] = (double)xv.x; xd[4 * j + 1] = (double)xv.y;
        xd[4 * j + 2] = (double)xv.z; xd[4 * j + 3] = (double)xv.w;
    }

    double dtot = 0.0;
#pragma unroll
    for (int p = 0; p < 4; ++p) {
        int mp = __shfl(m, p * 8 + (lane >> 3), 64);
        const float* pm = base + (size_t)mp * CC + cseg;
        double a = 0.0;
#pragma unroll
        for (int j = 0; j < 4; ++j) {
            float4 f = *(const float4*)(pm + 32 * j);
            a += xd[4 * j + 0] * (double)f.x + xd[4 * j + 1] * (double)f.y
               + xd[4 * j + 2] * (double)f.z + xd[4 * j + 3] * (double)f.w;
        }
        a += __shfl_xor(a, 1, 64);
        a += __shfl_xor(a, 2, 64);
        a += __shfl_xor(a, 4, 64);                   // 8-lane group sum -> full 128-ch dot
        double got = __shfl(a, (lane & 7) * 8 + (lane >> 3), 64);   // transpose collect
        if ((lane >> 3) == p) dtot = got;            // lane c (<32) holds dot of candidate c
    }

    double sv = act ? (2.0 * dtot - xxm) : -1.0e300;
    int si = act ? m : (0x40000000 + lane);          // unique sentinels
    float sx = 0.f, sy = 0.f;
#pragma unroll
    for (int rr = 0; rr < 10; ++rr) {
        double bv = sv; int bi = si;
#pragma unroll
        for (int off = 32; off; off >>= 1) {
            double ov = __shfl_xor(bv, off, 64);
            int oi = __shfl_xor(bi, off, 64);
            bool tk = (ov > bv) || (ov == bv && oi < bi);
            bv = tk ? ov : bv; bi = tk ? oi : bi;
        }
        float2 pm2 = *(const float2*)(base + (size_t)bi * CC + 2 * lane);
        sx += pm2.x; sy += pm2.y;                    // rank-order summation (as before)
        if (si == bi) sv = -1.0e301;                 // knock out winner (dup copies die together)
    }
    float2 o; o.x = sx * (1.f / KK); o.y = sy * (1.f / KK);
    *(float2*)(M + (size_t)r * CC + 2 * lane) = o;
}

// ---------------- y = Wa*M + (Wb-Wa)*h + bias ----------------
__global__ __launch_bounds__(256) void k_gemm(const float* __restrict__ M, const float* __restrict__ h,
                                              const float* __restrict__ W, const float* __restrict__ bias,
                                              float* __restrict__ y) {
    __shared__ float Ws[64][33];
    __shared__ float Xs[32][65];
    int b = blockIdx.z;
    int o0 = blockIdx.y * 64;
    int n0 = blockIdx.x * 64;
    int tid = threadIdx.x;
    int tx = tid & 15, ty = tid >> 4;
    float acc[4][4] = {};
    const float* Mb = M + (size_t)b * NN * CC;
    const float* hb = h + (size_t)b * CC * NN;

    for (int c0 = 0; c0 < CC; c0 += 32) {
        for (int i = tid; i < 64 * 32; i += 256) {
            int c = i & 31, o = i >> 5;
            Ws[o][c] = W[(size_t)(o0 + o) * TWO_CC + c0 + c];
        }
        for (int i = tid; i < 64 * 32; i += 256) {
            int c = i & 31, nn = i >> 5;
            Xs[c][nn] = Mb[(size_t)(n0 + nn) * CC + c0 + c];
        }
        __syncthreads();
        for (int c = 0; c < 32; ++c) {
            float a[4], bb[4];
#pragma unroll
            for (int q = 0; q < 4; ++q) { a[q] = Ws[ty * 4 + q][c]; bb[q] = Xs[c][tx * 4 + q]; }
#pragma unroll
            for (int i2 = 0; i2 < 4; ++i2)
#pragma unroll
                for (int j = 0; j < 4; ++j) acc[i2][j] += a[i2] * bb[j];
        }
        __syncthreads();
    }
    for (int c0 = 0; c0 < CC; c0 += 32) {
        for (int i = tid; i < 64 * 32; i += 256) {
            int c = i & 31, o = i >> 5;
            const float* wr = W + (size_t)(o0 + o) * TWO_CC;
            Ws[o][c] = wr[CC + c0 + c] - wr[c0 + c];
        }
        for (int i = tid; i < 64 * 32; i += 256) {
            int nn = i & 63, c = i >> 6;
            Xs[c][nn] = hb[(size_t)(c0 + c) * NN + n0 + nn];
        }
        __syncthreads();
        for (int c = 0; c < 32; ++c) {
            float a[4], bb[4];
#pragma unroll
            for (int q = 0; q < 4; ++q) { a[q] = Ws[ty * 4 + q][c]; bb[q] = Xs[c][tx * 4 + q]; }
#pragma unroll
            for (int i2 = 0; i2 < 4; ++i2)
#pragma unroll
                for (int j = 0; j < 4; ++j) acc[i2][j] += a[i2] * bb[j];
        }
        __syncthreads();
    }
#pragma unroll
    for (int i2 = 0; i2 < 4; ++i2) {
        int o = o0 + ty * 4 + i2;
        float bv = bias[o];
#pragma unroll
        for (int j = 0; j < 4; ++j)
            y[((size_t)b * CC + o) * NN + n0 + tx * 4 + j] = acc[i2][j] + bv;
    }
}

// ---------------- per-(b,o) mean/var(ddof=1), relu, optional residual ----------------
__global__ __launch_bounds__(256) void k_norm(const float* __restrict__ y, const float* __restrict__ res,
                                              float* __restrict__ out, int add_res) {
    int bo = blockIdx.x;
    const float* row = y + (size_t)bo * NN;
    float s = 0.f, s2 = 0.f;
    for (int n = threadIdx.x; n < NN; n += 256) {
        float v = row[n];
        s += v;
        s2 += v * v;
    }
#pragma unroll
    for (int off = 32; off > 0; off >>= 1) {
        s += __shfl_down(s, off, 64);
        s2 += __shfl_down(s2, off, 64);
    }
    __shared__ float ss[4], ss2[4];
    int wave = threadIdx.x >> 6, lane = threadIdx.x & 63;
    if (lane == 0) { ss[wave] = s; ss2[wave] = s2; }
    __syncthreads();
    if (threadIdx.x == 0) {
        float S = ss[0] + ss[1] + ss[2] + ss[3];
        float S2 = ss2[0] + ss2[1] + ss2[2] + ss2[3];
        float mean = S * (1.f / NN);
        float var = (S2 - S * mean) * (1.f / (NN - 1));
        ss[0] = mean;
        ss2[0] = rsqrtf(var + 1e-3f);
    }
    __syncthreads();
    float mean = ss[0], inv = ss2[0];
    for (int n = threadIdx.x; n < NN; n += 256) {
        float v = (row[n] - mean) * inv;
        v = fmaxf(v, 0.f);
        if (add_res) v += res[(size_t)bo * NN + n];
        out[(size_t)bo * NN + n] = v;
    }
}

extern "C" void kernel_launch(void* const* d_in, const int* in_sizes, int n_in,
                              void* d_out, int out_size, void* d_ws, size_t ws_size,
                              hipStream_t stream) {
    const float* x  = (const float*)d_in[0];
    const float* W1 = (const float*)d_in[1];
    const float* b1 = (const float*)d_in[2];
    const float* W2 = (const float*)d_in[3];
    const float* b2 = (const float*)d_in[4];
    float* out = (float*)d_out;

    char* wsb = (char*)d_ws;
    double* xx = (double*)wsb;                          // 8*2048 f64 = 131072 B
    char* p = wsb + (size_t)BB * NN * 8;
    float* ht = (float*)p;    p += (size_t)BB * NN * CC * 4;    // 8 MB f32 transposed
    float* Mw = (float*)p;    p += (size_t)BB * NN * CC * 4;    // 8 MB neighbor-mean
    float* y  = (float*)p;    p += (size_t)BB * CC * NN * 4;    // 8 MB
    float* h1 = (float*)p;                                      // 8 MB

    // bf16 hi/lo transposed arrays overlay M (consumed by k_knn before k_rg writes M)
    unsigned short* hti  = (unsigned short*)Mw;                 // 4 MB
    unsigned short* htlo = hti + (size_t)BB * NN * CC;          // 4 MB
    // screened keys + f32 norms overlay y (consumed before k_gemm writes y)
    unsigned* cand = (unsigned*)y;                              // 8*2*2048*16*4 = 2 MB
    float* xxf = (float*)((char*)y + (size_t)4 * 1024 * 1024);  // 64 KB

    auto layer = [&](const float* hin, const float* Wt, const float* bt, float* hout, int add_res) {
        hipLaunchKernelGGL(k_xx, dim3((BB * NN) / 256), dim3(256), 0, stream, hin, xx, xxf);
        hipLaunchKernelGGL(k_bf, dim3(NN / 32, CC / 32, BB), dim3(256), 0, stream, hin, ht, hti, htlo);
        hipLaunchKernelGGL(k_knn, dim3(NN / 64, MYS, BB), dim3(256), 0, stream, hti, htlo, xxf, cand);
        hipLaunchKernelGGL(k_rg, dim3(BB * NN / 4), dim3(256), 0, stream, ht, xx, cand, Mw);
        hipLaunchKernelGGL(k_gemm, dim3(NN / 64, CC / 64, BB), dim3(256), 0, stream, Mw, hin, Wt, bt, y);
        hipLaunchKernelGGL(k_norm, dim3(BB * CC), dim3(256), 0, stream, y, x, hout, add_res);
    };

    layer(x, W1, b1, h1, 0);
    layer(h1, W2, b2, out, 1);
}

// Round 7
// 400.053 us; speedup vs baseline: 3.0182x; 1.0359x over previous
//
#include <hip/hip_runtime.h>
#include <math.h>

#define BB 8
#define CC 128
#define NN 2048
#define KK 10
#define TWO_CC 256
#define DEP 16
#define MYS 2            // candidate-range halves per row (1024 each)

typedef __attribute__((ext_vector_type(8))) short bf16x8;
typedef __attribute__((ext_vector_type(4))) float f32x4;

// async global->LDS, 16B per lane; lds dest = wave-uniform base + lane*16
__device__ __forceinline__ void gload16(const void* g, void* l) {
    __builtin_amdgcn_global_load_lds((const __attribute__((address_space(1))) void*)g,
                                     (__attribute__((address_space(3))) void*)l, 16, 0, 0);
}

// round-to-nearest bf16
__device__ __forceinline__ unsigned short rtnbf(float v) {
    unsigned u = __float_as_uint(v);
    return (unsigned short)((u + 0x7FFFu + ((u >> 16) & 1u)) >> 16);
}

// descending top-16 insert of a packed u32 key
__device__ __forceinline__ void ins16(unsigned (&L)[DEP], unsigned k) {
    if (k > L[DEP - 1]) {
        L[DEP - 1] = k;
#pragma unroll
        for (int q = DEP - 1; q >= 1; --q) {
            unsigned a = L[q - 1], c = L[q];
            L[q - 1] = a > c ? a : c;
            L[q]     = a > c ? c : a;
        }
    }
}

// ---------------- squared column norms (f64 exact + f32 copy for the screen) ----------------
__global__ __launch_bounds__(256) void k_xx(const float* __restrict__ h, double* __restrict__ xx,
                                            float* __restrict__ xxf) {
    int t = blockIdx.x * 256 + threadIdx.x;
    if (t >= BB * NN) return;
    int b = t / NN, n = t % NN;
    const float* p = h + (size_t)b * CC * NN + n;
    double s = 0.0;
#pragma unroll
    for (int c = 0; c < CC; ++c) {
        double v = (double)p[(size_t)c * NN];
        s += v * v;
    }
    xx[t] = s;
    xxf[t] = (float)s;
}

// ---------------- fused transpose + bf16 hi split ----------------
// ht[b][n][c] = h[b][c][n] (f32); hti = RTN bf16 of the same (screen input only).
__global__ __launch_bounds__(256) void k_bf(const float* __restrict__ h, float* __restrict__ ht,
                                            unsigned short* __restrict__ hti) {
    __shared__ float tile[32][33];
    int b = blockIdx.z, c0 = blockIdx.y * 32, n0 = blockIdx.x * 32;
    int tx = threadIdx.x & 31, tyy = threadIdx.x >> 5;
    const float* hb = h + (size_t)b * CC * NN;
#pragma unroll
    for (int i = 0; i < 4; ++i)
        tile[tyy + i * 8][tx] = hb[(size_t)(c0 + tyy + i * 8) * NN + n0 + tx];
    __syncthreads();
    size_t ob = (size_t)b * NN * CC;
#pragma unroll
    for (int i = 0; i < 4; ++i) {
        int n = n0 + tyy + i * 8, c = c0 + tx;
        float v = tile[tx][tyy + i * 8];
        ht[ob + (size_t)n * CC + c] = v;
        hti[ob + (size_t)n * CC + c] = rtnbf(v);
    }
}

// ---------------- MFMA hi-only screen + packed-key top-16 per (row, half) ----------------
// block: 64 rows (n0..+63) x half my (1024 cands). 4 waves; wave owns 16 rows.
// LDS: A hi [64][128] bf16 (16KB) + B hi dbuf 2x[32][128] (2x8KB) = 32KB.
// XOR-swizzle ((row&7)<<4) on GLOBAL source (staging) and on ds_read addrs (both-sides).
// Screen error (~0.05 sigma) << shortlist demotion margin (~2); exact f64 refine re-ranks.
__global__ __launch_bounds__(256, 3) void k_knn(const unsigned short* __restrict__ hti,
                                                const float* __restrict__ xxf,
                                                unsigned* __restrict__ cand) {
    __shared__ __align__(16) char smem[32768];
    int t = threadIdx.x;
    int lane = t & 63, wv = t >> 6;
    int b = blockIdx.z, my = blockIdx.y, n0 = blockIdx.x * 64;

    const unsigned short* h0 = hti + (size_t)b * NN * CC;

    // ---- stage A-tile once (hi only, 16KB = 1024 slots) ----
#pragma unroll
    for (int q = 0; q < 4; ++q) {
        int sidx = q * 256 + wv * 64 + lane;
        int n = sidx >> 4, ch = sidx & 15;
        gload16(h0 + (size_t)(n0 + n) * CC + ((ch ^ (n & 7)) << 3),
                smem + (q * 256 + wv * 64) * 16);
    }

    auto stageB = [&](int mt, int buf) {
        int m0b = my * 1024 + mt * 32;
#pragma unroll
        for (int q = 0; q < 2; ++q) {
            int sidx = q * 256 + wv * 64 + lane;
            int mr = sidx >> 4, ch = sidx & 15;
            gload16(h0 + (size_t)(m0b + mr) * CC + ((ch ^ (mr & 7)) << 3),
                    smem + 16384 + buf * 8192 + (q * 256 + wv * 64) * 16);
        }
    };

    unsigned L[4][DEP];
#pragma unroll
    for (int r = 0; r < 4; ++r)
#pragma unroll
        for (int q = 0; q < DEP; ++q) L[r][q] = 0u;

    stageB(0, 0);
    __syncthreads();

    // hoist this wave's A fragments (16 rows x 128 k, hi)
    bf16x8 ahi[4];
    {
        int abase = (wv * 16 + (lane & 15)) * 256;
        int swz = (lane & 7) << 4;
#pragma unroll
        for (int ks = 0; ks < 4; ++ks) {
            int off = (abase + ks * 64 + ((lane >> 4) << 4)) ^ swz;
            ahi[ks] = *(const bf16x8*)(smem + off);
        }
    }

    const float* xb = xxf + b * NN;
    int buf = 0;
    for (int mt = 0; mt < 32; ++mt) {
        if (mt + 1 < 32) stageB(mt + 1, buf ^ 1);
        const char* Bb = smem + 16384 + buf * 8192;
        int m0 = my * 1024 + mt * 32;
#pragma unroll
        for (int cs = 0; cs < 2; ++cs) {
            float xm = xb[m0 + cs * 16 + (lane & 15)];
            f32x4 Cf = {0.f, 0.f, 0.f, 0.f};
            int rb = (cs * 16 + (lane & 15)) * 256;
            int swz = (lane & 7) << 4;
#pragma unroll
            for (int ks = 0; ks < 4; ++ks) {
                int off = (rb + ks * 64 + ((lane >> 4) << 4)) ^ swz;
                bf16x8 bh = *(const bf16x8*)(Bb + off);
                Cf = __builtin_amdgcn_mfma_f32_16x16x32_bf16(ahi[ks], bh, Cf, 0, 0, 0);
            }
            unsigned invrel = 1023u - (unsigned)(mt * 32 + cs * 16 + (lane & 15));
#pragma unroll
            for (int r = 0; r < 4; ++r) {
                float v = fmaf(2.f, Cf[r], -xm);
                unsigned u = __float_as_uint(v);
                u ^= (unsigned)((int)u >> 31) | 0x80000000u;
                ins16(L[r], (u & 0xFFFFFC00u) | invrel);
            }
        }
        __syncthreads();
        buf ^= 1;
    }

    // register bitonic merge across the 16 lanes of each row-group (masks 1,2,4,8)
#pragma unroll
    for (int r = 0; r < 4; ++r)
#pragma unroll
        for (int rnd = 0; rnd < 4; ++rnd) {
            unsigned C[DEP];
#pragma unroll
            for (int q = 0; q < DEP; ++q) {
                unsigned pv = (unsigned)__shfl_xor((int)L[r][DEP - 1 - q], 1 << rnd, 64);
                C[q] = L[r][q] > pv ? L[r][q] : pv;
            }
#pragma unroll
            for (int d = 8; d >= 1; d >>= 1)
#pragma unroll
                for (int i = 0; i < DEP; ++i)
                    if (!(i & d)) {
                        unsigned a = C[i], c2 = C[i + d];
                        C[i]     = a > c2 ? a : c2;
                        C[i + d] = a > c2 ? c2 : a;
                    }
#pragma unroll
            for (int q = 0; q < DEP; ++q) L[r][q] = C[q];
        }

    if ((lane & 15) == 0) {
        int g = lane >> 4;
#pragma unroll
        for (int r = 0; r < 4; ++r) {
            int n = n0 + wv * 16 + g * 4 + r;
            unsigned* op = cand + ((size_t)(b * MYS + my) * NN + n) * DEP;
#pragma unroll
            for (int q = 0; q < DEP; ++q) op[q] = L[r][q];
        }
    }
}

// ---------------- fused exact f64 re-score of 32 candidates + top-10 + f32 neighbor mean ----
// 4 waves/block, 1 row/wave. Lanes 0..31 own candidates (2 halves x 16).
__global__ __launch_bounds__(256) void k_rg(const float* __restrict__ ht, const double* __restrict__ xxg,
                                            const unsigned* __restrict__ cand, float* __restrict__ M) {
    int wv = threadIdx.x >> 6, lane = threadIdx.x & 63;
    int r = blockIdx.x * 4 + wv;
    int b = r >> 11, n = r & (NN - 1);
    const float* base = ht + (size_t)b * NN * CC;

    bool act = lane < 32;
    int half = (lane >> 4) & 1, q16 = lane & 15;
    int m = n;
    if (act) {
        unsigned key = cand[((size_t)(b * MYS + half) * NN + n) * DEP + q16];
        m = half * 1024 + 1023 - (int)(key & 1023u);
    }
    double xxm = xxg[b * NN + m];

    int cseg = (lane & 7) * 4;                       // this lane's 4-ch unit within each 32-ch block
    double xd[16];
#pragma unroll
    for (int j = 0; j < 4; ++j) {
        float4 xv = *(const float4*)(base + (size_t)n * CC + 32 * j + cseg);
        xd[4 * j + 0] = (double)xv.x; xd[4 * j + 1] = (double)xv.y;
        xd[4 * j + 2] = (double)xv.z; xd[4 * j + 3] = (double)xv.w;
    }

    double dtot = 0.0;
#pragma unroll
    for (int p = 0; p < 4; ++p) {
        int mp = __shfl(m, p * 8 + (lane >> 3), 64);
        const float* pm = base + (size_t)mp * CC + cseg;
        double a = 0.0;
#pragma unroll
        for (int j = 0; j < 4; ++j) {
            float4 f = *(const float4*)(pm + 32 * j);
            a += xd[4 * j + 0] * (double)f.x + xd[4 * j + 1] * (double)f.y
               + xd[4 * j + 2] * (double)f.z + xd[4 * j + 3] * (double)f.w;
        }
        a += __shfl_xor(a, 1, 64);
        a += __shfl_xor(a, 2, 64);
        a += __shfl_xor(a, 4, 64);                   // 8-lane group sum -> full 128-ch dot
        double got = __shfl(a, (lane & 7) * 8 + (lane >> 3), 64);   // transpose collect
        if ((lane >> 3) == p) dtot = got;            // lane c (<32) holds dot of candidate c
    }

    double sv = act ? (2.0 * dtot - xxm) : -1.0e300;
    int si = act ? m : (0x40000000 + lane);          // unique sentinels
    float sx = 0.f, sy = 0.f;
#pragma unroll
    for (int rr = 0; rr < 10; ++rr) {
        double bv = sv; int bi = si;
#pragma unroll
        for (int off = 32; off; off >>= 1) {
            double ov = __shfl_xor(bv, off, 64);
            int oi = __shfl_xor(bi, off, 64);
            bool tk = (ov > bv) || (ov == bv && oi < bi);
            bv = tk ? ov : bv; bi = tk ? oi : bi;
        }
        float2 pm2 = *(const float2*)(base + (size_t)bi * CC + 2 * lane);
        sx += pm2.x; sy += pm2.y;                    // rank-order summation (as before)
        if (si == bi) sv = -1.0e301;                 // knock out winner (dup copies die together)
    }
    float2 o; o.x = sx * (1.f / KK); o.y = sy * (1.f / KK);
    *(float2*)(M + (size_t)r * CC + 2 * lane) = o;
}

// ---------------- y = Wa*M + (Wb-Wa)*h + bias (exact f32 path) ----------------
__global__ __launch_bounds__(256) void k_gemm(const float* __restrict__ M, const float* __restrict__ h,
                                              const float* __restrict__ W, const float* __restrict__ bias,
                                              float* __restrict__ y) {
    __shared__ float Ws[64][33];
    __shared__ float Xs[32][65];
    int b = blockIdx.z;
    int o0 = blockIdx.y * 64;
    int n0 = blockIdx.x * 64;
    int tid = threadIdx.x;
    int tx = tid & 15, ty = tid >> 4;
    float acc[4][4] = {};
    const float* Mb = M + (size_t)b * NN * CC;
    const float* hb = h + (size_t)b * CC * NN;

    for (int c0 = 0; c0 < CC; c0 += 32) {
        for (int i = tid; i < 64 * 32; i += 256) {
            int c = i & 31, o = i >> 5;
            Ws[o][c] = W[(size_t)(o0 + o) * TWO_CC + c0 + c];
        }
        for (int i = tid; i < 64 * 32; i += 256) {
            int c = i & 31, nn = i >> 5;
            Xs[c][nn] = Mb[(size_t)(n0 + nn) * CC + c0 + c];
        }
        __syncthreads();
        for (int c = 0; c < 32; ++c) {
            float a[4], bb[4];
#pragma unroll
            for (int q = 0; q < 4; ++q) { a[q] = Ws[ty * 4 + q][c]; bb[q] = Xs[c][tx * 4 + q]; }
#pragma unroll
            for (int i2 = 0; i2 < 4; ++i2)
#pragma unroll
                for (int j = 0; j < 4; ++j) acc[i2][j] += a[i2] * bb[j];
        }
        __syncthreads();
    }
    for (int c0 = 0; c0 < CC; c0 += 32) {
        for (int i = tid; i < 64 * 32; i += 256) {
            int c = i & 31, o = i >> 5;
            const float* wr = W + (size_t)(o0 + o) * TWO_CC;
            Ws[o][c] = wr[CC + c0 + c] - wr[c0 + c];
        }
        for (int i = tid; i < 64 * 32; i += 256) {
            int nn = i & 63, c = i >> 6;
            Xs[c][nn] = hb[(size_t)(c0 + c) * NN + n0 + nn];
        }
        __syncthreads();
        for (int c = 0; c < 32; ++c) {
            float a[4], bb[4];
#pragma unroll
            for (int q = 0; q < 4; ++q) { a[q] = Ws[ty * 4 + q][c]; bb[q] = Xs[c][tx * 4 + q]; }
#pragma unroll
            for (int i2 = 0; i2 < 4; ++i2)
#pragma unroll
                for (int j = 0; j < 4; ++j) acc[i2][j] += a[i2] * bb[j];
        }
        __syncthreads();
    }
#pragma unroll
    for (int i2 = 0; i2 < 4; ++i2) {
        int o = o0 + ty * 4 + i2;
        float bv = bias[o];
#pragma unroll
        for (int j = 0; j < 4; ++j)
            y[((size_t)b * CC + o) * NN + n0 + tx * 4 + j] = acc[i2][j] + bv;
    }
}

// ---------------- per-(b,o) mean/var(ddof=1), relu, optional residual ----------------
__global__ __launch_bounds__(256) void k_norm(const float* __restrict__ y, const float* __restrict__ res,
                                              float* __restrict__ out, int add_res) {
    int bo = blockIdx.x;
    const float* row = y + (size_t)bo * NN;
    float s = 0.f, s2 = 0.f;
    for (int n = threadIdx.x; n < NN; n += 256) {
        float v = row[n];
        s += v;
        s2 += v * v;
    }
#pragma unroll
    for (int off = 32; off > 0; off >>= 1) {
        s += __shfl_down(s, off, 64);
        s2 += __shfl_down(s2, off, 64);
    }
    __shared__ float ss[4], ss2[4];
    int wave = threadIdx.x >> 6, lane = threadIdx.x & 63;
    if (lane == 0) { ss[wave] = s; ss2[wave] = s2; }
    __syncthreads();
    if (threadIdx.x == 0) {
        float S = ss[0] + ss[1] + ss[2] + ss[3];
        float S2 = ss2[0] + ss2[1] + ss2[2] + ss2[3];
        float mean = S * (1.f / NN);
        float var = (S2 - S * mean) * (1.f / (NN - 1));
        ss[0] = mean;
        ss2[0] = rsqrtf(var + 1e-3f);
    }
    __syncthreads();
    float mean = ss[0], inv = ss2[0];
    for (int n = threadIdx.x; n < NN; n += 256) {
        float v = (row[n] - mean) * inv;
        v = fmaxf(v, 0.f);
        if (add_res) v += res[(size_t)bo * NN + n];
        out[(size_t)bo * NN + n] = v;
    }
}

extern "C" void kernel_launch(void* const* d_in, const int* in_sizes, int n_in,
                              void* d_out, int out_size, void* d_ws, size_t ws_size,
                              hipStream_t stream) {
    const float* x  = (const float*)d_in[0];
    const float* W1 = (const float*)d_in[1];
    const float* b1 = (const float*)d_in[2];
    const float* W2 = (const float*)d_in[3];
    const float* b2 = (const float*)d_in[4];
    float* out = (float*)d_out;

    char* p = (char*)d_ws;
    double* xx = (double*)p;   p += (size_t)BB * NN * 8;          // 128 KB
    float* xxf = (float*)p;    p += (size_t)BB * NN * 4;          // 64 KB
    float* ht = (float*)p;     p += (size_t)BB * NN * CC * 4;     // 8 MB f32 transposed
    float* Mw = (float*)p;     p += (size_t)BB * NN * CC * 4;     // 8 MB neighbor-mean (f32)
    float* y  = (float*)p;     p += (size_t)BB * CC * NN * 4;     // 8 MB
    float* h1 = (float*)p;                                        // 8 MB

    // overlays (lifetime-disjoint):
    // hti (4 MB, screen input) lives in M's region — consumed by k_knn before k_rg writes M.
    // cand (2 MB) lives in y's region — consumed by k_rg before k_gemm writes y.
    unsigned short* hti = (unsigned short*)Mw;
    unsigned* cand = (unsigned*)y;

    auto layer = [&](const float* hin, const float* Wt, const float* bt, float* hout, int add_res) {
        hipLaunchKernelGGL(k_xx, dim3((BB * NN) / 256), dim3(256), 0, stream, hin, xx, xxf);
        hipLaunchKernelGGL(k_bf, dim3(NN / 32, CC / 32, BB), dim3(256), 0, stream, hin, ht, hti);
        hipLaunchKernelGGL(k_knn, dim3(NN / 64, MYS, BB), dim3(256), 0, stream, hti, xxf, cand);
        hipLaunchKernelGGL(k_rg, dim3(BB * NN / 4), dim3(256), 0, stream, ht, xx, cand, Mw);
        hipLaunchKernelGGL(k_gemm, dim3(NN / 64, CC / 64, BB), dim3(256), 0, stream, Mw, hin, Wt, bt, y);
        hipLaunchKernelGGL(k_norm, dim3(BB * CC), dim3(256), 0, stream, y, x, hout, add_res);
    };

    layer(x, W1, b1, h1, 0);
    layer(h1, W2, b2, out, 1);
}

// Round 8
// 337.778 us; speedup vs baseline: 3.5747x; 1.1844x over previous
//
#include <hip/hip_runtime.h>
#include <math.h>

#define BB 8
#define CC 128
#define NN 2048
#define KK 10
#define TWO_CC 256
#define DEP 12
#define MYS 2            // candidate-range halves per row (1024 each)

typedef __attribute__((ext_vector_type(8))) short bf16x8;
typedef __attribute__((ext_vector_type(4))) float f32x4;

// async global->LDS, 16B per lane; lds dest = wave-uniform base + lane*16
__device__ __forceinline__ void gload16(const void* g, void* l) {
    __builtin_amdgcn_global_load_lds((const __attribute__((address_space(1))) void*)g,
                                     (__attribute__((address_space(3))) void*)l, 16, 0, 0);
}

// round-to-nearest bf16
__device__ __forceinline__ unsigned short rtnbf(float v) {
    unsigned u = __float_as_uint(v);
    return (unsigned short)((u + 0x7FFFu + ((u >> 16) & 1u)) >> 16);
}

// descending top-12 insert of a packed u32 key
__device__ __forceinline__ void ins12(unsigned (&L)[DEP], unsigned k) {
    if (k > L[DEP - 1]) {
        L[DEP - 1] = k;
#pragma unroll
        for (int q = DEP - 1; q >= 1; --q) {
            unsigned a = L[q - 1], c = L[q];
            L[q - 1] = a > c ? a : c;
            L[q]     = a > c ? c : a;
        }
    }
}

// ---------------- squared column norms (f64 exact + f32 copy for the screen) ----------------
__global__ __launch_bounds__(256) void k_xx(const float* __restrict__ h, double* __restrict__ xx,
                                            float* __restrict__ xxf) {
    int t = blockIdx.x * 256 + threadIdx.x;
    if (t >= BB * NN) return;
    int b = t / NN, n = t % NN;
    const float* p = h + (size_t)b * CC * NN + n;
    double s = 0.0;
#pragma unroll
    for (int c = 0; c < CC; ++c) {
        double v = (double)p[(size_t)c * NN];
        s += v * v;
    }
    xx[t] = s;
    xxf[t] = (float)s;
}

// ---------------- fused transpose + bf16 hi split ----------------
// ht[b][n][c] = h[b][c][n] (f32); hti = RTN bf16 of the same (screen input only).
__global__ __launch_bounds__(256) void k_bf(const float* __restrict__ h, float* __restrict__ ht,
                                            unsigned short* __restrict__ hti) {
    __shared__ float tile[32][33];
    int b = blockIdx.z, c0 = blockIdx.y * 32, n0 = blockIdx.x * 32;
    int tx = threadIdx.x & 31, tyy = threadIdx.x >> 5;
    const float* hb = h + (size_t)b * CC * NN;
#pragma unroll
    for (int i = 0; i < 4; ++i)
        tile[tyy + i * 8][tx] = hb[(size_t)(c0 + tyy + i * 8) * NN + n0 + tx];
    __syncthreads();
    size_t ob = (size_t)b * NN * CC;
#pragma unroll
    for (int i = 0; i < 4; ++i) {
        int n = n0 + tyy + i * 8, c = c0 + tx;
        float v = tile[tx][tyy + i * 8];
        ht[ob + (size_t)n * CC + c] = v;
        hti[ob + (size_t)n * CC + c] = rtnbf(v);
    }
}

// ---------------- MFMA hi-only screen + packed-key top-12 per (row, half) ----------------
// block: 64 rows (n0..+63) x half my (1024 cands). 4 waves; wave owns 16 rows.
// LDS: A hi [64][128] bf16 (16KB) + B hi dbuf 2x[32][128] (2x8KB) = 32KB.
// XOR-swizzle ((row&7)<<4) on GLOBAL source (staging) and on ds_read addrs (both-sides).
// Safety: per-lane depth = merged depth = 12 (exact at both levels); merged 12/half
// requires a >=3-rank screen-noise jump to drop a true top-10 member (sigma~0.1, gaps O(1)).
__global__ __launch_bounds__(256, 3) void k_knn(const unsigned short* __restrict__ hti,
                                                const float* __restrict__ xxf,
                                                unsigned* __restrict__ cand) {
    __shared__ __align__(16) char smem[32768];
    int t = threadIdx.x;
    int lane = t & 63, wv = t >> 6;
    int b = blockIdx.z, my = blockIdx.y, n0 = blockIdx.x * 64;

    const unsigned short* h0 = hti + (size_t)b * NN * CC;

    // ---- stage A-tile once (hi only, 16KB = 1024 slots) ----
#pragma unroll
    for (int q = 0; q < 4; ++q) {
        int sidx = q * 256 + wv * 64 + lane;
        int n = sidx >> 4, ch = sidx & 15;
        gload16(h0 + (size_t)(n0 + n) * CC + ((ch ^ (n & 7)) << 3),
                smem + (q * 256 + wv * 64) * 16);
    }

    auto stageB = [&](int mt, int buf) {
        int m0b = my * 1024 + mt * 32;
#pragma unroll
        for (int q = 0; q < 2; ++q) {
            int sidx = q * 256 + wv * 64 + lane;
            int mr = sidx >> 4, ch = sidx & 15;
            gload16(h0 + (size_t)(m0b + mr) * CC + ((ch ^ (mr & 7)) << 3),
                    smem + 16384 + buf * 8192 + (q * 256 + wv * 64) * 16);
        }
    };

    unsigned L[4][DEP];
#pragma unroll
    for (int r = 0; r < 4; ++r)
#pragma unroll
        for (int q = 0; q < DEP; ++q) L[r][q] = 0u;

    stageB(0, 0);
    __syncthreads();

    // hoist this wave's A fragments (16 rows x 128 k, hi)
    bf16x8 ahi[4];
    {
        int abase = (wv * 16 + (lane & 15)) * 256;
        int swz = (lane & 7) << 4;
#pragma unroll
        for (int ks = 0; ks < 4; ++ks) {
            int off = (abase + ks * 64 + ((lane >> 4) << 4)) ^ swz;
            ahi[ks] = *(const bf16x8*)(smem + off);
        }
    }

    const float* xb = xxf + b * NN;
    int buf = 0;
    for (int mt = 0; mt < 32; ++mt) {
        if (mt + 1 < 32) stageB(mt + 1, buf ^ 1);
        const char* Bb = smem + 16384 + buf * 8192;
        int m0 = my * 1024 + mt * 32;
#pragma unroll
        for (int cs = 0; cs < 2; ++cs) {
            float xm = xb[m0 + cs * 16 + (lane & 15)];
            f32x4 Cf = {0.f, 0.f, 0.f, 0.f};
            int rb = (cs * 16 + (lane & 15)) * 256;
            int swz = (lane & 7) << 4;
#pragma unroll
            for (int ks = 0; ks < 4; ++ks) {
                int off = (rb + ks * 64 + ((lane >> 4) << 4)) ^ swz;
                bf16x8 bh = *(const bf16x8*)(Bb + off);
                Cf = __builtin_amdgcn_mfma_f32_16x16x32_bf16(ahi[ks], bh, Cf, 0, 0, 0);
            }
            unsigned invrel = 1023u - (unsigned)(mt * 32 + cs * 16 + (lane & 15));
#pragma unroll
            for (int r = 0; r < 4; ++r) {
                float v = fmaf(2.f, Cf[r], -xm);
                unsigned u = __float_as_uint(v);
                u ^= (unsigned)((int)u >> 31) | 0x80000000u;
                ins12(L[r], (u & 0xFFFFFC00u) | invrel);
            }
        }
        __syncthreads();
        buf ^= 1;
    }

    // merge across the 16 lanes of each row-group: pad lists to 16 with 0-sentinels,
    // register bitonic merge (masks 1,2,4,8); top-12 of the union survives exactly.
#pragma unroll
    for (int r = 0; r < 4; ++r) {
        unsigned T[16];
#pragma unroll
        for (int q = 0; q < DEP; ++q) T[q] = L[r][q];
#pragma unroll
        for (int q = DEP; q < 16; ++q) T[q] = 0u;
#pragma unroll
        for (int rnd = 0; rnd < 4; ++rnd) {
            unsigned C[16];
#pragma unroll
            for (int q = 0; q < 16; ++q) {
                unsigned pv = (unsigned)__shfl_xor((int)T[15 - q], 1 << rnd, 64);
                C[q] = T[q] > pv ? T[q] : pv;
            }
#pragma unroll
            for (int d = 8; d >= 1; d >>= 1)
#pragma unroll
                for (int i = 0; i < 16; ++i)
                    if (!(i & d)) {
                        unsigned a = C[i], c2 = C[i + d];
                        C[i]     = a > c2 ? a : c2;
                        C[i + d] = a > c2 ? c2 : a;
                    }
#pragma unroll
            for (int q = 0; q < 16; ++q) T[q] = C[q];
        }
        if ((lane & 15) == 0) {
            int n = n0 + wv * 16 + (lane >> 4) * 4 + r;
            unsigned* op = cand + ((size_t)(b * MYS + my) * NN + n) * DEP;
#pragma unroll
            for (int q = 0; q < DEP; ++q) op[q] = T[q];
        }
    }
}

// ---------------- fused exact f64 re-score of 24 candidates + top-10 + f32 neighbor mean ----
// 4 waves/block, 1 row/wave. Lanes 0..23 own candidates (2 halves x 12).
// Top-10 via rank-by-counting (readlane broadcasts, no serial shfl chains) + ds_permute.
__global__ __launch_bounds__(256) void k_rg(const float* __restrict__ ht, const double* __restrict__ xxg,
                                            const unsigned* __restrict__ cand, float* __restrict__ M) {
    int wv = threadIdx.x >> 6, lane = threadIdx.x & 63;
    int r = blockIdx.x * 4 + wv;
    int b = r >> 11, n = r & (NN - 1);
    const float* base = ht + (size_t)b * NN * CC;

    bool act = lane < 2 * DEP;                       // 24 candidates
    int half = (lane >= DEP) ? 1 : 0;
    int q12 = lane - DEP * half;
    int m = n;
    if (act) {
        unsigned key = cand[((size_t)(b * MYS + half) * NN + n) * DEP + q12];
        m = half * 1024 + 1023 - (int)(key & 1023u);
    }
    double xxm = xxg[b * NN + m];

    int cseg = (lane & 7) * 4;                       // this lane's 4-ch unit within each 32-ch block
    double xd[16];
#pragma unroll
    for (int j = 0; j < 4; ++j) {
        float4 xv = *(const float4*)(base + (size_t)n * CC + 32 * j + cseg);
        xd[4 * j + 0] = (double)xv.x; xd[4 * j + 1] = (double)xv.y;
        xd[4 * j + 2] = (double)xv.z; xd[4 * j + 3] = (double)xv.w;
    }

    double dtot = 0.0;
#pragma unroll
    for (int p = 0; p < 3; ++p) {                    // 3 passes x 8 candidates
        int mp = __shfl(m, p * 8 + (lane >> 3), 64);
        const float* pm = base + (size_t)mp * CC + cseg;
        double a = 0.0;
#pragma unroll
        for (int j = 0; j < 4; ++j) {
            float4 f = *(const float4*)(pm + 32 * j);
            a += xd[4 * j + 0] * (double)f.x + xd[4 * j + 1] * (double)f.y
               + xd[4 * j + 2] * (double)f.z + xd[4 * j + 3] * (double)f.w;
        }
        a += __shfl_xor(a, 1, 64);
        a += __shfl_xor(a, 2, 64);
        a += __shfl_xor(a, 4, 64);                   // 8-lane group sum -> full 128-ch dot
        double got = __shfl(a, (lane & 7) * 8 + (lane >> 3), 64);   // transpose collect
        if ((lane >> 3) == p) dtot = got;            // lane c (<24) holds dot of candidate c
    }

    double sv = act ? (2.0 * dtot - xxm) : -1.0e300;
    int si = act ? m : (0x40000000 + lane);          // unique sentinels

    // rank = number of candidates strictly better under (v desc, idx asc) — same total
    // order as the old knockout loop. Broadcasts are compile-time-lane readlanes.
    int rank = 0;
#pragma unroll
    for (int c = 0; c < 2 * DEP; ++c) {
        double sc = __shfl(sv, c, 64);
        int ic = __shfl(si, c, 64);
        if ((sc > sv) || (sc == sv && ic < si)) ++rank;
    }
    // push m to lane=rank; ranks of active lanes are unique in 0..23.
    int mbr = __builtin_amdgcn_ds_permute(rank << 2, m);

    float sx = 0.f, sy = 0.f;
#pragma unroll
    for (int rr = 0; rr < 10; ++rr) {                // rank-order summation (as before)
        int mr = __shfl(mbr, rr, 64);
        float2 pm2 = *(const float2*)(base + (size_t)mr * CC + 2 * lane);
        sx += pm2.x; sy += pm2.y;
    }
    float2 o; o.x = sx * (1.f / KK); o.y = sy * (1.f / KK);
    *(float2*)(M + (size_t)r * CC + 2 * lane) = o;
}

// ---------------- y = Wa*M + (Wb-Wa)*h + bias (exact f32 path) ----------------
__global__ __launch_bounds__(256) void k_gemm(const float* __restrict__ M, const float* __restrict__ h,
                                              const float* __restrict__ W, const float* __restrict__ bias,
                                              float* __restrict__ y) {
    __shared__ float Ws[64][33];
    __shared__ float Xs[32][65];
    int b = blockIdx.z;
    int o0 = blockIdx.y * 64;
    int n0 = blockIdx.x * 64;
    int tid = threadIdx.x;
    int tx = tid & 15, ty = tid >> 4;
    float acc[4][4] = {};
    const float* Mb = M + (size_t)b * NN * CC;
    const float* hb = h + (size_t)b * CC * NN;

    for (int c0 = 0; c0 < CC; c0 += 32) {
        for (int i = tid; i < 64 * 32; i += 256) {
            int c = i & 31, o = i >> 5;
            Ws[o][c] = W[(size_t)(o0 + o) * TWO_CC + c0 + c];
        }
        for (int i = tid; i < 64 * 32; i += 256) {
            int c = i & 31, nn = i >> 5;
            Xs[c][nn] = Mb[(size_t)(n0 + nn) * CC + c0 + c];
        }
        __syncthreads();
        for (int c = 0; c < 32; ++c) {
            float a[4], bb[4];
#pragma unroll
            for (int q = 0; q < 4; ++q) { a[q] = Ws[ty * 4 + q][c]; bb[q] = Xs[c][tx * 4 + q]; }
#pragma unroll
            for (int i2 = 0; i2 < 4; ++i2)
#pragma unroll
                for (int j = 0; j < 4; ++j) acc[i2][j] += a[i2] * bb[j];
        }
        __syncthreads();
    }
    for (int c0 = 0; c0 < CC; c0 += 32) {
        for (int i = tid; i < 64 * 32; i += 256) {
            int c = i & 31, o = i >> 5;
            const float* wr = W + (size_t)(o0 + o) * TWO_CC;
            Ws[o][c] = wr[CC + c0 + c] - wr[c0 + c];
        }
        for (int i = tid; i < 64 * 32; i += 256) {
            int nn = i & 63, c = i >> 6;
            Xs[c][nn] = hb[(size_t)(c0 + c) * NN + n0 + nn];
        }
        __syncthreads();
        for (int c = 0; c < 32; ++c) {
            float a[4], bb[4];
#pragma unroll
            for (int q = 0; q < 4; ++q) { a[q] = Ws[ty * 4 + q][c]; bb[q] = Xs[c][tx * 4 + q]; }
#pragma unroll
            for (int i2 = 0; i2 < 4; ++i2)
#pragma unroll
                for (int j = 0; j < 4; ++j) acc[i2][j] += a[i2] * bb[j];
        }
        __syncthreads();
    }
#pragma unroll
    for (int i2 = 0; i2 < 4; ++i2) {
        int o = o0 + ty * 4 + i2;
        float bv = bias[o];
#pragma unroll
        for (int j = 0; j < 4; ++j)
            y[((size_t)b * CC + o) * NN + n0 + tx * 4 + j] = acc[i2][j] + bv;
    }
}

// ---------------- per-(b,o) mean/var(ddof=1), relu, optional residual ----------------
__global__ __launch_bounds__(256) void k_norm(const float* __restrict__ y, const float* __restrict__ res,
                                              float* __restrict__ out, int add_res) {
    int bo = blockIdx.x;
    const float* row = y + (size_t)bo * NN;
    float s = 0.f, s2 = 0.f;
    for (int n = threadIdx.x; n < NN; n += 256) {
        float v = row[n];
        s += v;
        s2 += v * v;
    }
#pragma unroll
    for (int off = 32; off > 0; off >>= 1) {
        s += __shfl_down(s, off, 64);
        s2 += __shfl_down(s2, off, 64);
    }
    __shared__ float ss[4], ss2[4];
    int wave = threadIdx.x >> 6, lane = threadIdx.x & 63;
    if (lane == 0) { ss[wave] = s; ss2[wave] = s2; }
    __syncthreads();
    if (threadIdx.x == 0) {
        float S = ss[0] + ss[1] + ss[2] + ss[3];
        float S2 = ss2[0] + ss2[1] + ss2[2] + ss2[3];
        float mean = S * (1.f / NN);
        float var = (S2 - S * mean) * (1.f / (NN - 1));
        ss[0] = mean;
        ss2[0] = rsqrtf(var + 1e-3f);
    }
    __syncthreads();
    float mean = ss[0], inv = ss2[0];
    for (int n = threadIdx.x; n < NN; n += 256) {
        float v = (row[n] - mean) * inv;
        v = fmaxf(v, 0.f);
        if (add_res) v += res[(size_t)bo * NN + n];
        out[(size_t)bo * NN + n] = v;
    }
}

extern "C" void kernel_launch(void* const* d_in, const int* in_sizes, int n_in,
                              void* d_out, int out_size, void* d_ws, size_t ws_size,
                              hipStream_t stream) {
    const float* x  = (const float*)d_in[0];
    const float* W1 = (const float*)d_in[1];
    const float* b1 = (const float*)d_in[2];
    const float* W2 = (const float*)d_in[3];
    const float* b2 = (const float*)d_in[4];
    float* out = (float*)d_out;

    char* p = (char*)d_ws;
    double* xx = (double*)p;   p += (size_t)BB * NN * 8;          // 128 KB
    float* xxf = (float*)p;    p += (size_t)BB * NN * 4;          // 64 KB
    float* ht = (float*)p;     p += (size_t)BB * NN * CC * 4;     // 8 MB f32 transposed
    float* Mw = (float*)p;     p += (size_t)BB * NN * CC * 4;     // 8 MB neighbor-mean (f32)
    float* y  = (float*)p;     p += (size_t)BB * CC * NN * 4;     // 8 MB
    float* h1 = (float*)p;                                        // 8 MB

    // overlays (lifetime-disjoint):
    // hti (4 MB, screen input) lives in M's region — consumed by k_knn before k_rg writes M.
    // cand (1.6 MB) lives in y's region — consumed by k_rg before k_gemm writes y.
    unsigned short* hti = (unsigned short*)Mw;
    unsigned* cand = (unsigned*)y;

    auto layer = [&](const float* hin, const float* Wt, const float* bt, float* hout, int add_res) {
        hipLaunchKernelGGL(k_xx, dim3((BB * NN) / 256), dim3(256), 0, stream, hin, xx, xxf);
        hipLaunchKernelGGL(k_bf, dim3(NN / 32, CC / 32, BB), dim3(256), 0, stream, hin, ht, hti);
        hipLaunchKernelGGL(k_knn, dim3(NN / 64, MYS, BB), dim3(256), 0, stream, hti, xxf, cand);
        hipLaunchKernelGGL(k_rg, dim3(BB * NN / 4), dim3(256), 0, stream, ht, xx, cand, Mw);
        hipLaunchKernelGGL(k_gemm, dim3(NN / 64, CC / 64, BB), dim3(256), 0, stream, Mw, hin, Wt, bt, y);
        hipLaunchKernelGGL(k_norm, dim3(BB * CC), dim3(256), 0, stream, y, x, hout, add_res);
    };

    layer(x, W1, b1, h1, 0);
    layer(h1, W2, b2, out, 1);
}